// Round 8
// baseline (105.237 us; speedup 1.0000x reference)
//
#include <hip/hip_runtime.h>
#include <hip/hip_bf16.h>
#include <stdint.h>

#define BATCH   32768
#define NBLK    8
#define BIN     256
#define BOUT    256
#define XCOLS   2048      // NBLK*BIN
#define BM      32
#define BK      64
#define KSTEPS  4         // BIN/BK
#define EPAD    260       // 256 + 4 pad

typedef short bf16x8_t __attribute__((ext_vector_type(8)));
typedef float f32x4_t  __attribute__((ext_vector_type(4)));

// ---------------- prepass: W fp32 [8][256][256] -> frag-linear bf16 ----------------
// elem index = ((((n*4 + kk)*2 + ks)*16 + wgrp)*64 + lane)*8 + j
__global__ __launch_bounds__(256) void prep_w_kernel(
    const float* __restrict__ W, unsigned short* __restrict__ Wsz) {
  int idx = blockIdx.x * 256 + threadIdx.x;   // 0 .. 2^19-1
  int j    = idx & 7;
  int l    = (idx >> 3) & 63;
  int wgrp = (idx >> 9) & 15;
  int ks   = (idx >> 13) & 1;
  int kk   = (idx >> 14) & 3;
  int n    = idx >> 16;
  int o = wgrp * 16 + (l & 15);
  int k = kk * 64 + ks * 32 + (l >> 4) * 8 + j;
  float v = W[((size_t)(n * 256 + o) * 256) + k];
  uint32_t bits = __builtin_bit_cast(uint32_t, v);
  Wsz[idx] = (unsigned short)((bits + 0x7FFFu + ((bits >> 16) & 1u)) >> 16);  // RNE
}

// ---------------- main kernel: BM=32, 4 WGs/CU, counted-vmcnt pipeline -------------
// acc[2][4]=32 regs + single-buffered W frags (32 regs) => ~100/wave, fits the
// (256,4) 128-reg budget WITHOUT the R4/R5 spill (those had 64-reg acc).
// If profile shows VGPR_Count==64 + FETCH balloon, the allocator spilled: revert.
__global__ __launch_bounds__(256, 4) void blocklinear_kernel(
    const float* __restrict__ x, const unsigned short* __restrict__ Wsz,
    const float* __restrict__ bias, float* __restrict__ y) {
  // smem: two 8KB X-tile buffers (fp32); epilogue reuses as 16 x EPAD f32.
  __shared__ __align__(16) float smem[(2 * BM * BK) > (16 * EPAD) ? (2 * BM * BK) : (16 * EPAD)];

  const int wgid = blockIdx.x;
  const int n    = wgid & 7;        // block id fastest: XCD c keeps W-block c L2-hot
  const int mt   = wgid >> 3;
  const int m0   = mt * BM;
  const int tid  = threadIdx.x;
  const int wave = tid >> 6;
  const int lane = tid & 63;
  const int fr   = lane & 15;
  const int fq   = lane >> 4;

  f32x4_t acc[2][4];
#pragma unroll
  for (int mf = 0; mf < 2; ++mf)
#pragma unroll
    for (int nf = 0; nf < 4; ++nf)
      acc[mf][nf] = (f32x4_t){0.f, 0.f, 0.f, 0.f};

  const float* xg = x + (size_t)m0 * XCOLS + n * BIN;
  const unsigned short* wl =
      Wsz + (size_t)n * (KSTEPS * 2 * 16 * 64 * 8) + ((wave * 4) << 9) + (lane << 3);

#define FENCE __builtin_amdgcn_sched_barrier(0)
#define BAR   __builtin_amdgcn_s_barrier()

// X tile = 32 rows x 64 f32 = 512 16B-slots; 2 gload_lds per thread.
#define STAGE_X(kk, buf)                                                      \
  {                                                                           \
    _Pragma("unroll")                                                         \
    for (int i = 0; i < 2; ++i) {                                             \
      int s = i * 256 + tid;                                                  \
      int row = s >> 4;                                                       \
      int c = s & 15;                                                         \
      int srcslot = c ^ (row & 15);                                           \
      const float* gp = xg + (size_t)row * XCOLS + (kk) * BK + srcslot * 4;   \
      __builtin_amdgcn_global_load_lds(                                       \
          (const __attribute__((address_space(1))) void*)gp,                  \
          (__attribute__((address_space(3))) void*)&smem[(buf) * 2048 + s * 4], \
          16, 0, 0);                                                          \
    }                                                                         \
  }

#define LOAD_W(kk, wreg)                                                      \
  {                                                                           \
    _Pragma("unroll")                                                         \
    for (int ks = 0; ks < 2; ++ks)                                            \
      _Pragma("unroll")                                                       \
      for (int nf = 0; nf < 4; ++nf)                                          \
        wreg[ks][nf] = *(const bf16x8_t*)&wl[(((kk) * 2 + ks) * 16 + nf) << 9]; \
  }

#define COMPUTE(xbuf, wreg)                                                   \
  {                                                                           \
    _Pragma("unroll")                                                         \
    for (int ks = 0; ks < 2; ++ks) {                                          \
      _Pragma("unroll")                                                       \
      for (int mf = 0; mf < 2; ++mf) {                                        \
        int row = mf * 16 + fr;                                               \
        int slot0 = ks * 8 + fq * 2;                                          \
        union { f32x4_t f; uint32_t u[4]; } A0, A1;                           \
        A0.f = *(const f32x4_t*)&xbuf[(row * 16 + ((slot0)     ^ (row & 15))) * 4]; \
        A1.f = *(const f32x4_t*)&xbuf[(row * 16 + ((slot0 + 1) ^ (row & 15))) * 4]; \
        union { uint32_t u[4]; bf16x8_t v; } af;                              \
        af.u[0] = ((A0.u[0] + 0x8000u) >> 16) | ((A0.u[1] + 0x8000u) & 0xFFFF0000u); \
        af.u[1] = ((A0.u[2] + 0x8000u) >> 16) | ((A0.u[3] + 0x8000u) & 0xFFFF0000u); \
        af.u[2] = ((A1.u[0] + 0x8000u) >> 16) | ((A1.u[1] + 0x8000u) & 0xFFFF0000u); \
        af.u[3] = ((A1.u[2] + 0x8000u) >> 16) | ((A1.u[3] + 0x8000u) & 0xFFFF0000u); \
        _Pragma("unroll")                                                     \
        for (int nf = 0; nf < 4; ++nf)                                        \
          acc[mf][nf] = __builtin_amdgcn_mfma_f32_16x16x32_bf16(              \
              af.v, wreg[ks][nf], acc[mf][nf], 0, 0, 0);                      \
      }                                                                       \
    }                                                                         \
  }

  bf16x8_t w[2][4];   // single W buffer; reg-dep serializes reload vs use
  const float* xs0 = &smem[0];
  const float* xs1 = &smem[2048];

  // Counted-vmcnt pipeline: per tile 2 X gload_lds + 8 W reg-loads.
  // After {X(kk):2, W(kk):8, X(kk+1):2} the wait for X(kk) is vmcnt(10);
  // the compiler's W-reg dep wait resolves at vmcnt(2), leaving X(kk+1) in flight.
  STAGE_X(0, 0);
  LOAD_W(0, w); STAGE_X(1, 1);
  FENCE; asm volatile("s_waitcnt vmcnt(10)"); FENCE; BAR; FENCE;   // X(0) ready
  COMPUTE(xs0, w);
  FENCE; BAR; FENCE;                                               // xs0 free
  LOAD_W(1, w); STAGE_X(2, 0);
  FENCE; asm volatile("s_waitcnt vmcnt(10)"); FENCE; BAR; FENCE;   // X(1) ready
  COMPUTE(xs1, w);
  FENCE; BAR; FENCE;                                               // xs1 free
  LOAD_W(2, w); STAGE_X(3, 1);
  FENCE; asm volatile("s_waitcnt vmcnt(10)"); FENCE; BAR; FENCE;   // X(2) ready
  COMPUTE(xs0, w);
  FENCE; BAR; FENCE;
  LOAD_W(3, w);
  FENCE; asm volatile("s_waitcnt vmcnt(8)"); FENCE; BAR; FENCE;    // X(3) ready
  COMPUTE(xs1, w);

#undef STAGE_X
#undef LOAD_W
#undef COMPUTE
#undef FENCE
#undef BAR

  // ---- epilogue: LDS transpose -> fully contiguous 16B/lane NT stores ----
  // acc[mf][nf][r] = y[m0 + mf*16 + fq*4 + r][n*256 + wave*64 + nf*16 + fr]
  float bv[4];
#pragma unroll
  for (int nf = 0; nf < 4; ++nf)
    bv[nf] = bias[n * BOUT + wave * 64 + nf * 16 + fr];

  float* ybase = y + (size_t)m0 * XCOLS + n * BOUT;
#pragma unroll
  for (int round = 0; round < 2; ++round) {
    __syncthreads();   // smem free (compute done / previous round fully read)
    {
      int mf = round;
#pragma unroll
      for (int nf = 0; nf < 4; ++nf)
#pragma unroll
        for (int r = 0; r < 4; ++r)
          smem[(fq * 4 + r) * EPAD + wave * 64 + nf * 16 + fr] =
              acc[mf][nf][r] + bv[nf];
    }
    __syncthreads();
    // 16 rows x 64 float4-chunks; consecutive lanes -> consecutive 16B of one
    // row => 1KB contiguous per wave-instruction.
#pragma unroll
    for (int i = 0; i < 4; ++i) {
      int s = i * 256 + tid;
      int row = s >> 6;
      int chunk = s & 63;
      f32x4_t v = *(const f32x4_t*)&smem[row * EPAD + chunk * 4];
      __builtin_nontemporal_store(
          v, (f32x4_t*)&ybase[(size_t)(round * 16 + row) * XCOLS + chunk * 4]);
    }
  }
}

// ---------------- fallback (ws too small): correct but slow fp32 ----------------
__global__ __launch_bounds__(256) void fallback_kernel(
    const float* __restrict__ x, const float* __restrict__ W,
    const float* __restrict__ b, float* __restrict__ y) {
  __shared__ float xrow[BIN];
  int row = blockIdx.x >> 3;
  int n   = blockIdx.x & 7;
  xrow[threadIdx.x] = x[(size_t)row * XCOLS + n * BIN + threadIdx.x];
  __syncthreads();
  const float* w = W + (size_t)(n * BOUT + threadIdx.x) * BIN;
  float s = b[n * BOUT + threadIdx.x];
  for (int i = 0; i < BIN; ++i) s += xrow[i] * w[i];
  y[(size_t)row * XCOLS + n * BIN + threadIdx.x] = s;
}

extern "C" void kernel_launch(void* const* d_in, const int* in_sizes, int n_in,
                              void* d_out, int out_size, void* d_ws, size_t ws_size,
                              hipStream_t stream) {
  const float* x = (const float*)d_in[0];
  const float* W = (const float*)d_in[1];
  const float* b = (const float*)d_in[2];
  float* y = (float*)d_out;

  const size_t ws_needed = (size_t)NBLK * KSTEPS * 2 * 16 * 64 * 8 * sizeof(unsigned short); // 1 MB
  if (ws_size >= ws_needed) {
    unsigned short* Wsz = (unsigned short*)d_ws;
    prep_w_kernel<<<2048, 256, 0, stream>>>(W, Wsz);
    blocklinear_kernel<<<(BATCH / BM) * NBLK, 256, 0, stream>>>(x, Wsz, b, y);
  } else {
    fallback_kernel<<<BATCH * NBLK, 256, 0, stream>>>(x, W, b, y);
  }
}

// Round 9
// 96.085 us; speedup vs baseline: 1.0953x; 1.0953x over previous
//
#include <hip/hip_runtime.h>
#include <hip/hip_bf16.h>
#include <stdint.h>

#define BATCH   32768
#define NBLK    8
#define BIN     256
#define BOUT    256
#define XCOLS   2048      // NBLK*BIN
#define BM      64
#define BK      64
#define KSTEPS  4         // BIN/BK
#define EPAD    260       // 256 + 4 pad

typedef short bf16x8_t __attribute__((ext_vector_type(8)));
typedef float f32x4_t  __attribute__((ext_vector_type(4)));

// ---------------- prepass: W fp32 [8][256][256] -> frag-linear bf16 ----------------
__global__ __launch_bounds__(256) void prep_w_kernel(
    const float* __restrict__ W, unsigned short* __restrict__ Wsz) {
  int idx = blockIdx.x * 256 + threadIdx.x;   // 0 .. 2^19-1
  int j    = idx & 7;
  int l    = (idx >> 3) & 63;
  int wgrp = (idx >> 9) & 15;
  int ks   = (idx >> 13) & 1;
  int kk   = (idx >> 14) & 3;
  int n    = idx >> 16;
  int o = wgrp * 16 + (l & 15);
  int k = kk * 64 + ks * 32 + (l >> 4) * 8 + j;
  float v = W[((size_t)(n * 256 + o) * 256) + k];
  uint32_t bits = __builtin_bit_cast(uint32_t, v);
  Wsz[idx] = (unsigned short)((bits + 0x7FFFu + ((bits >> 16) & 1u)) >> 16);  // RNE
}

// ---------------- main kernel: R7 + store-drain-free epilogue ----------------------
// __launch_bounds__(256,3) is load-bearing: (256,4) -> 128-reg budget -> spill
// (R4/R5 regression). LDS 33.3KB; regs bind at 3 waves/SIMD.
__global__ __launch_bounds__(256, 3) void blocklinear_kernel(
    const float* __restrict__ x, const unsigned short* __restrict__ Wsz,
    const float* __restrict__ bias, float* __restrict__ y) {
  // smem: [0..8191] = two 16KB X tile buffers; epilogue reuses as 32xEPAD f32.
  __shared__ __align__(16) float smem[2 * BM * BK > 32 * EPAD ? 2 * BM * BK : 32 * EPAD];

  const int wgid = blockIdx.x;
  const int n    = wgid & 7;        // block id fastest: XCD c keeps W-block c L2-hot
  const int mt   = wgid >> 3;
  const int m0   = mt * BM;
  const int tid  = threadIdx.x;
  const int wave = tid >> 6;
  const int lane = tid & 63;
  const int fr   = lane & 15;
  const int fq   = lane >> 4;

  f32x4_t acc[4][4];
#pragma unroll
  for (int mf = 0; mf < 4; ++mf)
#pragma unroll
    for (int nf = 0; nf < 4; ++nf)
      acc[mf][nf] = (f32x4_t){0.f, 0.f, 0.f, 0.f};

  const float* xg = x + (size_t)m0 * XCOLS + n * BIN;
  const unsigned short* wl =
      Wsz + (size_t)n * (KSTEPS * 2 * 16 * 64 * 8) + ((wave * 4) << 9) + (lane << 3);

#define FENCE __builtin_amdgcn_sched_barrier(0)
#define BAR   __builtin_amdgcn_s_barrier()

#define STAGE_X(kk, buf)                                                      \
  {                                                                           \
    _Pragma("unroll")                                                         \
    for (int i = 0; i < 4; ++i) {                                             \
      int s = i * 256 + tid;                                                  \
      int row = s >> 4;                                                       \
      int c = s & 15;                                                         \
      int srcslot = c ^ (row & 15);                                           \
      const float* gp = xg + (size_t)row * XCOLS + (kk) * BK + srcslot * 4;   \
      __builtin_amdgcn_global_load_lds(                                       \
          (const __attribute__((address_space(1))) void*)gp,                  \
          (__attribute__((address_space(3))) void*)&smem[(buf) * 4096 + (i * 256 + wave * 64) * 4], \
          16, 0, 0);                                                          \
    }                                                                         \
  }

#define LOAD_W(kk, wreg)                                                      \
  {                                                                           \
    _Pragma("unroll")                                                         \
    for (int ks = 0; ks < 2; ++ks)                                            \
      _Pragma("unroll")                                                       \
      for (int nf = 0; nf < 4; ++nf)                                          \
        wreg[ks][nf] = *(const bf16x8_t*)&wl[(((kk) * 2 + ks) * 16 + nf) << 9]; \
  }

#define COMPUTE(xbuf, wreg)                                                   \
  {                                                                           \
    _Pragma("unroll")                                                         \
    for (int ks = 0; ks < 2; ++ks) {                                          \
      _Pragma("unroll")                                                       \
      for (int mf = 0; mf < 4; ++mf) {                                        \
        int row = mf * 16 + fr;                                               \
        int slot0 = ks * 8 + fq * 2;                                          \
        union { f32x4_t f; uint32_t u[4]; } A0, A1;                           \
        A0.f = *(const f32x4_t*)&xbuf[(row * 16 + ((slot0)     ^ (row & 15))) * 4]; \
        A1.f = *(const f32x4_t*)&xbuf[(row * 16 + ((slot0 + 1) ^ (row & 15))) * 4]; \
        union { uint32_t u[4]; bf16x8_t v; } af;                              \
        af.u[0] = ((A0.u[0] + 0x8000u) >> 16) | ((A0.u[1] + 0x8000u) & 0xFFFF0000u); \
        af.u[1] = ((A0.u[2] + 0x8000u) >> 16) | ((A0.u[3] + 0x8000u) & 0xFFFF0000u); \
        af.u[2] = ((A1.u[0] + 0x8000u) >> 16) | ((A1.u[1] + 0x8000u) & 0xFFFF0000u); \
        af.u[3] = ((A1.u[2] + 0x8000u) >> 16) | ((A1.u[3] + 0x8000u) & 0xFFFF0000u); \
        _Pragma("unroll")                                                     \
        for (int nf = 0; nf < 4; ++nf)                                        \
          acc[mf][nf] = __builtin_amdgcn_mfma_f32_16x16x32_bf16(              \
              af.v, wreg[ks][nf], acc[mf][nf], 0, 0, 0);                      \
      }                                                                       \
    }                                                                         \
  }

  bf16x8_t wA[2][4], wB[2][4];
  const float* xs0 = &smem[0];
  const float* xs1 = &smem[4096];

  // R6/R7 pipeline unchanged: counted vmcnt, X(kk+1) in flight across COMPUTE(kk).
  STAGE_X(0, 0);
  LOAD_W(0, wA); STAGE_X(1, 1);
  FENCE; asm volatile("s_waitcnt vmcnt(12)"); FENCE; BAR; FENCE;   // X(0) ready
  COMPUTE(xs0, wA);
  FENCE; BAR; FENCE;                                               // xs0 free
  LOAD_W(1, wB); STAGE_X(2, 0);
  FENCE; asm volatile("s_waitcnt vmcnt(12)"); FENCE; BAR; FENCE;   // X(1) ready
  COMPUTE(xs1, wB);
  FENCE; BAR; FENCE;                                               // xs1 free
  LOAD_W(2, wA); STAGE_X(3, 1);
  FENCE; asm volatile("s_waitcnt vmcnt(12)"); FENCE; BAR; FENCE;   // X(2) ready
  COMPUTE(xs0, wA);
  FENCE; BAR; FENCE;
  LOAD_W(3, wB);
  FENCE; asm volatile("s_waitcnt vmcnt(8)"); FENCE; BAR; FENCE;    // X(3) ready
  COMPUTE(xs1, wB);

#undef STAGE_X
#undef LOAD_W
#undef COMPUTE

  // ---- epilogue: LDS transpose -> contiguous NT stores; NO vmcnt drains ----
  // __syncthreads would insert s_waitcnt vmcnt(0) and stall on in-flight NT
  // stores (full HBM write latency). LDS ordering only needs lgkmcnt(0)+BAR:
  // each wave waits its own ds ops, barrier syncs arrival; stores fire-and-forget.
#define LBAR { FENCE; asm volatile("s_waitcnt lgkmcnt(0)"); FENCE; BAR; FENCE; }

  float bv[4];
#pragma unroll
  for (int nf = 0; nf < 4; ++nf)
    bv[nf] = bias[n * BOUT + wave * 64 + nf * 16 + fr];

  float* ybase = y + (size_t)m0 * XCOLS + n * BOUT;
#pragma unroll
  for (int round = 0; round < 2; ++round) {
    LBAR;   // smem free: all waves' prior ds_reads (X / previous round) done
#pragma unroll
    for (int h = 0; h < 2; ++h) {
      int mf = round * 2 + h;
#pragma unroll
      for (int nf = 0; nf < 4; ++nf)
#pragma unroll
        for (int r = 0; r < 4; ++r)
          smem[(h * 16 + fq * 4 + r) * EPAD + wave * 64 + nf * 16 + fr] =
              acc[mf][nf][r] + bv[nf];
    }
    LBAR;   // all transpose writes visible
    // 32 rows x 64 float4-chunks; consecutive lanes -> consecutive 16B of one
    // row => 1KB contiguous per wave-instruction.
#pragma unroll
    for (int i = 0; i < 8; ++i) {
      int s = i * 256 + tid;
      int row = s >> 6;
      int chunk = s & 63;
      f32x4_t v = *(const f32x4_t*)&smem[row * EPAD + chunk * 4];
      __builtin_nontemporal_store(
          v, (f32x4_t*)&ybase[(size_t)(round * 32 + row) * XCOLS + chunk * 4]);
    }
  }
#undef LBAR
#undef FENCE
#undef BAR
}

// ---------------- fallback (ws too small): correct but slow fp32 ----------------
__global__ __launch_bounds__(256) void fallback_kernel(
    const float* __restrict__ x, const float* __restrict__ W,
    const float* __restrict__ b, float* __restrict__ y) {
  __shared__ float xrow[BIN];
  int row = blockIdx.x >> 3;
  int n   = blockIdx.x & 7;
  xrow[threadIdx.x] = x[(size_t)row * XCOLS + n * BIN + threadIdx.x];
  __syncthreads();
  const float* w = W + (size_t)(n * BOUT + threadIdx.x) * BIN;
  float s = b[n * BOUT + threadIdx.x];
  for (int i = 0; i < BIN; ++i) s += xrow[i] * w[i];
  y[(size_t)row * XCOLS + n * BIN + threadIdx.x] = s;
}

extern "C" void kernel_launch(void* const* d_in, const int* in_sizes, int n_in,
                              void* d_out, int out_size, void* d_ws, size_t ws_size,
                              hipStream_t stream) {
  const float* x = (const float*)d_in[0];
  const float* W = (const float*)d_in[1];
  const float* b = (const float*)d_in[2];
  float* y = (float*)d_out;

  const size_t ws_needed = (size_t)NBLK * KSTEPS * 2 * 16 * 64 * 8 * sizeof(unsigned short); // 1 MB
  if (ws_size >= ws_needed) {
    unsigned short* Wsz = (unsigned short*)d_ws;
    prep_w_kernel<<<2048, 256, 0, stream>>>(W, Wsz);
    blocklinear_kernel<<<(BATCH / BM) * NBLK, 256, 0, stream>>>(x, Wsz, b, y);
  } else {
    fallback_kernel<<<BATCH * NBLK, 256, 0, stream>>>(x, W, b, y);
  }
}